// Round 6
// baseline (1545.928 us; speedup 1.0000x reference)
//
#include <hip/hip_runtime.h>
#include <math.h>

#define NTOK 32768      // B*T
#define DD 256
#define MM 400
#define BB 64
#define TT 512
#define TOK 32          // tokens per K1 block (both modalities)
#define KC 16           // K chunk

// workspace layout (bytes)
#define WS_PH     0          // float [2][64][400]
#define WS_ROWCNT 204800     // int   [2][64][400]
#define WS_HIST   409600     // int   [2][400]
#define WS_ERR    412800     // float [4][64]  slotted error sums
#define WS_ZERO_BYTES 413824
#define WS_ESQ    413824     // float [400]
#define WS_LG     415424     // float [2][64][400]
#define WS_SC     620224     // float [64][64]
#define WS_MODE   636608     // int   [128]

// ---------------------------------------------------------------- e_sq
__global__ void k_esq(const float* __restrict__ emb, float* __restrict__ esq) {
    int m = blockIdx.x, lane = threadIdx.x;
    float s = 0.f;
    for (int k = lane; k < DD; k += 64) { float e = emb[m * DD + k]; s += e * e; }
    #pragma unroll
    for (int off = 1; off < 64; off <<= 1) s += __shfl_xor(s, off, 64);
    if (lane == 0) esq[m] = s;
}

// ---------------------------------------------------------------- main fused kernel
// 1024 blocks; block = 32 tokens x BOTH modalities. 4 waves; wave owns 8
// tokens; lane tx owns codes m = tx+64j, j=0..6. e tile staged in LDS once
// per kc and reused for both modalities (448 FMA per 7 ds_read_b128).
// Epilogue also does quantized-output write + all 4 error sums (k_err fused).
//
// NOTE: plain __launch_bounds__(256) (no min-waves arg!) — rounds 2-4 proved
// (256,N) blocks promote-alloca and sends acc to scratch. Two separate
// [8][7] acc arrays (round-5-proven promotable size each).
__launch_bounds__(256)
__global__ void k1_main(const float* __restrict__ a, const float* __restrict__ v,
                        const float* __restrict__ emb, const float* __restrict__ esq_g,
                        float* __restrict__ pH_g, int* __restrict__ rowcnt,
                        float* __restrict__ outA, float* __restrict__ outV,
                        float* __restrict__ err) {
    __shared__ __align__(16) float e_c[MM * KC];    // 25.6 KB
    __shared__ float pH_w[8 * MM];                  // 12.8 KB
    __shared__ int ia_s[TOK], iv_s[TOK];
    __shared__ float er_s[4][4];

    const int tid = threadIdx.x;
    const int tx  = tid & 63;
    const int wv  = tid >> 6;
    const int bx  = blockIdx.x;        // 0..1023
    const int n0  = bx * TOK;
    const int b   = bx >> 4;           // batch row (16 blocks of 32 tokens per T=512)
    const int tok0 = n0 + wv * 8;
    // wave-uniform x bases, scalarized so main-loop loads use SGPR base
    const float* aw = a + (size_t)__builtin_amdgcn_readfirstlane(tok0) * DD;
    const float* vw = v + (size_t)__builtin_amdgcn_readfirstlane(tok0) * DD;

    int mj[7]; float esq[7]; int ebase[7]; int esw[7]; bool val[7];
    #pragma unroll
    for (int j = 0; j < 7; ++j) {
        int m = tx + 64 * j;
        val[j] = (m < MM);
        int mc = val[j] ? m : (MM - 1);
        mj[j] = mc;
        ebase[j] = mc * KC;
        esw[j] = ((mc >> 1) & 3) << 2;   // conflict-free read swizzle
        esq[j] = esq_g[mc];
    }

    float accA[8][7], accV[8][7];
    #pragma unroll
    for (int i = 0; i < 8; ++i)
        #pragma unroll
        for (int j = 0; j < 7; ++j) { accA[i][j] = 0.f; accV[i][j] = 0.f; }

    for (int kc = 0; kc < DD / KC; ++kc) {
        __syncthreads();
        // stage e chunk: lane map (m = (u&15)+16*(u>>6), K4 = ((u>>4)&3)<<2)
        // makes the swizzled LDS writes 2-way max (free); global side still
        // reads 64B contiguous per row.
        #pragma unroll
        for (int it = 0; it < 7; ++it) {
            int u = it * 256 + tid;
            if (u < MM * (KC / 4)) {
                int m  = (u & 15) + ((u >> 6) << 4);
                int K4 = ((u >> 4) & 3) << 2;
                float4 t4 = *(const float4*)(emb + (size_t)m * DD + kc * KC + K4);
                int sw = ((m >> 1) & 3) << 2;
                *(float4*)&e_c[m * KC + (K4 ^ sw)] = t4;
            }
        }
        __syncthreads();

        #pragma unroll
        for (int kg = 0; kg < KC / 4; ++kg) {
            const int K4 = kg << 2;
            float4 eb[7];
            #pragma unroll
            for (int j = 0; j < 7; ++j)
                eb[j] = *(const float4*)&e_c[ebase[j] + (K4 ^ esw[j])];
            const int koff = kc * KC + K4;
            #pragma unroll
            for (int i = 0; i < 8; ++i) {
                float4 xa = *(const float4*)(aw + (size_t)i * DD + koff);
                #pragma unroll
                for (int j = 0; j < 7; ++j) {
                    accA[i][j] = fmaf(xa.x, eb[j].x, accA[i][j]);
                    accA[i][j] = fmaf(xa.y, eb[j].y, accA[i][j]);
                    accA[i][j] = fmaf(xa.z, eb[j].z, accA[i][j]);
                    accA[i][j] = fmaf(xa.w, eb[j].w, accA[i][j]);
                }
            }
            #pragma unroll
            for (int i = 0; i < 8; ++i) {
                float4 xv = *(const float4*)(vw + (size_t)i * DD + koff);
                #pragma unroll
                for (int j = 0; j < 7; ++j) {
                    accV[i][j] = fmaf(xv.x, eb[j].x, accV[i][j]);
                    accV[i][j] = fmaf(xv.y, eb[j].y, accV[i][j]);
                    accV[i][j] = fmaf(xv.z, eb[j].z, accV[i][j]);
                    accV[i][j] = fmaf(xv.w, eb[j].w, accV[i][j]);
                }
            }
        }
    }

    float pacc_a[7], pacc_v[7];
    #pragma unroll
    for (int j = 0; j < 7; ++j) { pacc_a[j] = 0.f; pacc_v[j] = 0.f; }

    // Per-token epilogue, i as LITERAL constant (macro) so acc arrays stay
    // statically indexed (promote-alloca requirement).
#define EPI1(i, ACC, XBASE, ROWBASE, IDXARR, PACC) { \
        const int n = tok0 + i; \
        float4 xr = *(const float4*)(XBASE + (size_t)n * DD + tx * 4); \
        float xs = xr.x * xr.x + xr.y * xr.y + xr.z * xr.z + xr.w * xr.w; \
        _Pragma("unroll") \
        for (int off = 1; off < 64; off <<= 1) xs += __shfl_xor(xs, off, 64); \
        float sc[7]; \
        _Pragma("unroll") \
        for (int j = 0; j < 7; ++j) sc[j] = fmaf(-2.f, ACC[i][j], esq[j]); \
        float best = 1e30f; int bidx = 0x7fffffff; \
        _Pragma("unroll") \
        for (int j = 0; j < 7; ++j) \
            if (val[j] && sc[j] < best) { best = sc[j]; bidx = mj[j]; } \
        _Pragma("unroll") \
        for (int off = 1; off < 64; off <<= 1) { \
            float ob = __shfl_xor(best, off, 64); \
            int   oi = __shfl_xor(bidx, off, 64); \
            if (ob < best || (ob == best && oi < bidx)) { best = ob; bidx = oi; } \
        } \
        float z[7]; float zmax = -1e30f; \
        _Pragma("unroll") \
        for (int j = 0; j < 7; ++j) { \
            z[j] = -sqrtf(fmaxf(xs + sc[j], 0.f)); \
            if (val[j]) zmax = fmaxf(zmax, z[j]); \
        } \
        _Pragma("unroll") \
        for (int off = 1; off < 64; off <<= 1) \
            zmax = fmaxf(zmax, __shfl_xor(zmax, off, 64)); \
        float ee[7]; float se = 0.f; \
        _Pragma("unroll") \
        for (int j = 0; j < 7; ++j) { \
            ee[j] = val[j] ? __expf(z[j] - zmax) : 0.f; \
            se += ee[j]; \
        } \
        _Pragma("unroll") \
        for (int off = 1; off < 64; off <<= 1) se += __shfl_xor(se, off, 64); \
        float inv = 1.f / se; \
        _Pragma("unroll") \
        for (int j = 0; j < 7; ++j) PACC[j] += ee[j] * inv; \
        if (tx == 0) { \
            IDXARR[wv * 8 + i] = bidx; \
            atomicAdd(&rowcnt[(size_t)(ROWBASE + b) * MM + bidx], 1); \
        } \
    }
#define EPI(i) EPI1(i, accA, a, 0, ia_s, pacc_a) EPI1(i, accV, v, BB, iv_s, pacc_v)

    EPI(0) EPI(1) EPI(2) EPI(3) EPI(4) EPI(5) EPI(6) EPI(7)
#undef EPI
#undef EPI1

    // combine pH across waves, one global atomic per (mod, code)
    #pragma unroll
    for (int j = 0; j < 7; ++j)
        if (val[j]) {
            pH_w[wv * MM + mj[j]] = pacc_a[j];
            pH_w[(4 + wv) * MM + mj[j]] = pacc_v[j];
        }
    __syncthreads();
    for (int m = tid; m < MM; m += 256) {
        float sa = pH_w[m] + pH_w[MM + m] + pH_w[2 * MM + m] + pH_w[3 * MM + m];
        float sv = pH_w[4 * MM + m] + pH_w[5 * MM + m] + pH_w[6 * MM + m] + pH_w[7 * MM + m];
        atomicAdd(&pH_g[(size_t)b * MM + m], sa);
        atomicAdd(&pH_g[(size_t)(BB + b) * MM + m], sv);
    }

    // fused k_err: quantized-output write + 4 error sums (ia_s/iv_s visible
    // after the barrier above)
    float saa = 0.f, sav = 0.f, svv = 0.f, sva = 0.f;
    #pragma unroll
    for (int t8 = 0; t8 < 8; ++t8) {
        int tl = wv * 8 + t8;
        int n  = n0 + tl;
        int ia = ia_s[tl], iv = iv_s[tl];
        float4 xa4 = *(const float4*)(a + (size_t)n * DD + tx * 4);
        float4 xv4 = *(const float4*)(v + (size_t)n * DD + tx * 4);
        float4 qa4 = *(const float4*)(emb + (size_t)ia * DD + tx * 4);
        float4 qv4 = *(const float4*)(emb + (size_t)iv * DD + tx * 4);
        *(float4*)(outA + (size_t)n * DD + tx * 4) = qa4;
        *(float4*)(outV + (size_t)n * DD + tx * 4) = qv4;
        { float dx = xa4.x-qa4.x, dy = xa4.y-qa4.y, dz = xa4.z-qa4.z, dw = xa4.w-qa4.w;
          saa += dx*dx + dy*dy + dz*dz + dw*dw; }
        { float dx = xa4.x-qv4.x, dy = xa4.y-qv4.y, dz = xa4.z-qv4.z, dw = xa4.w-qv4.w;
          sav += dx*dx + dy*dy + dz*dz + dw*dw; }
        { float dx = xv4.x-qv4.x, dy = xv4.y-qv4.y, dz = xv4.z-qv4.z, dw = xv4.w-qv4.w;
          svv += dx*dx + dy*dy + dz*dz + dw*dw; }
        { float dx = xv4.x-qa4.x, dy = xv4.y-qa4.y, dz = xv4.z-qa4.z, dw = xv4.w-qa4.w;
          sva += dx*dx + dy*dy + dz*dz + dw*dw; }
    }
    #pragma unroll
    for (int off = 1; off < 64; off <<= 1) {
        saa += __shfl_xor(saa, off, 64);
        sav += __shfl_xor(sav, off, 64);
        svv += __shfl_xor(svv, off, 64);
        sva += __shfl_xor(sva, off, 64);
    }
    if (tx == 0) { er_s[wv][0] = saa; er_s[wv][1] = sav; er_s[wv][2] = svv; er_s[wv][3] = sva; }
    __syncthreads();
    if (tid < 4) {
        float s = er_s[0][tid] + er_s[1][tid] + er_s[2][tid] + er_s[3][tid];
        atomicAdd(&err[tid * 64 + (bx & 63)], s);
    }
}

// ---------------------------------------------------------------- normalize pH + logs; row modes; global hist
__global__ void k2_fuse(float* __restrict__ pH, float* __restrict__ Lg,
                        const int* __restrict__ rowcnt, int* __restrict__ modes,
                        int* __restrict__ hist) {
    int bx = blockIdx.x, tid = threadIdx.x;
    int i = bx * 256 + tid;
    if (i < 2 * BB * MM) {
        float p = pH[i] * (1.f / TT);
        pH[i] = p;
        Lg[i] = logf(p + 1e-10f);
    }
    if (bx < 2 * BB) {
        int lane = tid & 63, w = tid >> 6;
        const int* cnt = rowcnt + (size_t)bx * MM;
        if (w == 0) {
            int bc = -1, bi = 0x7fffffff;
            for (int m = lane; m < MM; m += 64) {
                int c = cnt[m];
                if (c > bc) { bc = c; bi = m; }
            }
            #pragma unroll
            for (int off = 1; off < 64; off <<= 1) {
                int oc = __shfl_xor(bc, off, 64);
                int oi = __shfl_xor(bi, off, 64);
                if (oc > bc || (oc == bc && oi < bi)) { bc = oc; bi = oi; }
            }
            if (lane == 0) modes[bx] = bi;
        } else if (w == 1) {
            for (int m = lane; m < MM; m += 64)
                atomicAdd(&hist[(bx >> 6) * MM + m], cnt[m]);
        }
    }
}

// ---------------------------------------------------------------- Scode (64x64, K=400, x2 terms)
__global__ void k4_scode(const float* __restrict__ pH, const float* __restrict__ Lg,
                         float* __restrict__ Sc) {
    int i = blockIdx.x;
    int tid = threadIdx.x, lane = tid & 63, wv = tid >> 6;
    const float* aPH = pH + (size_t)i * MM;
    const float* vPH = pH + (size_t)(BB + i) * MM;
    for (int jj = 0; jj < 16; ++jj) {
        int j = wv * 16 + jj;
        const float* Lv = Lg + (size_t)(BB + j) * MM;
        const float* La = Lg + (size_t)j * MM;
        float s = 0.f;
        for (int m = lane; m < MM; m += 64)
            s += aPH[m] * Lv[m] + vPH[m] * La[m];
        #pragma unroll
        for (int off = 1; off < 64; off <<= 1) s += __shfl_xor(s, off, 64);
        if (lane == 0) Sc[i * BB + j] = s;
    }
}

// ---------------------------------------------------------------- final scalars
__global__ void k5_final(const float* __restrict__ Sc, const int* __restrict__ hist,
                         const float* __restrict__ err, const int* __restrict__ modes,
                         float* __restrict__ outs) {
    __shared__ float red[4];
    __shared__ float mx_sh;
    int tid = threadIdx.x;
    int lane = tid & 63, wv = tid >> 6;

    float lmin = 1e30f;
    for (int i = tid; i < BB * BB; i += 256) lmin = fminf(lmin, Sc[i]);
    #pragma unroll
    for (int off = 1; off < 64; off <<= 1) lmin = fminf(lmin, __shfl_xor(lmin, off, 64));
    if (lane == 0) red[wv] = lmin;
    __syncthreads();
    if (tid == 0) mx_sh = -fminf(fminf(red[0], red[1]), fminf(red[2], red[3]));
    __syncthreads();
    float Mx = mx_sh;

    if (wv == 0) {
        int i = lane;
        float rs = 0.f;
        for (int j = 0; j < BB; ++j) rs += __expf(Sc[i * BB + j] + Mx);
        float dg = __expf(Sc[i * BB + i] + Mx);
        float term = logf(dg / (rs + 1e-5f));
        #pragma unroll
        for (int off = 1; off < 64; off <<= 1) term += __shfl_xor(term, off, 64);
        if (lane == 0) outs[4] = 0.5f * (-(term / (float)BB));
    } else if (wv == 1 || wv == 2) {
        int mod = wv - 1;
        float s = 0.f;
        for (int m = lane; m < MM; m += 64) {
            float p = (float)hist[mod * MM + m] * (1.f / (float)NTOK);
            s += p * logf(p + 1e-10f);
        }
        #pragma unroll
        for (int off = 1; off < 64; off <<= 1) s += __shfl_xor(s, off, 64);
        if (lane == 0) outs[2 + mod] = __expf(-s);
    } else {
        float e0 = err[0 * 64 + lane], e1 = err[1 * 64 + lane];
        float e2 = err[2 * 64 + lane], e3 = err[3 * 64 + lane];
        int eq = (modes[lane] == modes[BB + lane]) ? 1 : 0;
        #pragma unroll
        for (int off = 1; off < 64; off <<= 1) {
            e0 += __shfl_xor(e0, off, 64);
            e1 += __shfl_xor(e1, off, 64);
            e2 += __shfl_xor(e2, off, 64);
            e3 += __shfl_xor(e3, off, 64);
            eq += __shfl_xor(eq, off, 64);
        }
        if (lane == 0) {
            outs[5] = (float)eq;
            const float inv = 1.f / (float)((size_t)NTOK * DD);
            float a_e = e0 * inv, av_e = e1 * inv;
            float v_e = e2 * inv, va_e = e3 * inv;
            outs[0] = 0.5f * a_e + 0.25f * av_e;
            outs[1] = 0.5f * v_e + 0.25f * va_e;
        }
    }
}

// ----------------------------------------------------------------
extern "C" void kernel_launch(void* const* d_in, const int* in_sizes, int n_in,
                              void* d_out, int out_size, void* d_ws, size_t ws_size,
                              hipStream_t stream) {
    (void)in_sizes; (void)n_in; (void)out_size; (void)ws_size;
    const float* a   = (const float*)d_in[0];
    const float* v   = (const float*)d_in[1];
    const float* emb = (const float*)d_in[2];
    float* out = (float*)d_out;
    char* ws = (char*)d_ws;

    float* pH_g   = (float*)(ws + WS_PH);
    int*   rowcnt = (int*)(ws + WS_ROWCNT);
    int*   hist   = (int*)(ws + WS_HIST);
    float* err    = (float*)(ws + WS_ERR);
    float* esq    = (float*)(ws + WS_ESQ);
    float* Lg     = (float*)(ws + WS_LG);
    float* Sc     = (float*)(ws + WS_SC);
    int*   modes  = (int*)(ws + WS_MODE);

    hipMemsetAsync(d_ws, 0, WS_ZERO_BYTES, stream);
    k_esq<<<MM, 64, 0, stream>>>(emb, esq);
    k1_main<<<1024, 256, 0, stream>>>(a, v, emb, esq, pH_g, rowcnt,
                                      out, out + (size_t)NTOK * DD, err);
    k2_fuse<<<200, 256, 0, stream>>>(pH_g, Lg, rowcnt, modes, hist);
    k4_scode<<<BB, 256, 0, stream>>>(pH_g, Lg, Sc);
    k5_final<<<1, 256, 0, stream>>>(Sc, hist, err, modes, out + (size_t)2 * NTOK * DD);
}